// Round 6
// baseline (2970.375 us; speedup 1.0000x reference)
//
#include <hip/hip_runtime.h>
#include <hip/hip_fp16.h>

// Persistent-kernel autoregressive LSTM for MI355X (gfx950).  Round 6.
//
// R5 post-mortem: window ~6us; producer->consumer chain still had WG-wide
// rendezvous + single-wave combine + scattered h-stores (WRITE_SIZE rose from
// partial-line RMW). R6: operand-swapped MFMA -- weights are the A-operand
// with gate-rows packed [unit][gate], so D gives each lane all 4 gates of one
// (unit,batch) pair in its 4 acc regs. Gate math is lane-local; waves split
// K 2-way x batch 4-way; kh-pairs reduce via LDS flag handshake (no
// syncthreads); kh=1 waves combine/store/arrive autonomously (LDS counter,
// last-of-4 publishes slot). h layout [k/4][b][4] -> one 128B contiguous
// store per wave. cond-A windows are fully barrier-free (certification for
// h1r moved to a waitall-first window B on cond steps).

typedef unsigned short u16;
typedef unsigned int u32;
typedef _Float16 f16;
typedef _Float16 h8 __attribute__((ext_vector_type(8)));
typedef _Float16 h4 __attribute__((ext_vector_type(4)));
typedef float f4 __attribute__((ext_vector_type(4)));

#define HSZ 65536  // u16 per h slot: layout [256 kgrp][64 b][4 k]

static __device__ __forceinline__ f4 mfma16(h8 a, h8 b, f4 c) {
  return __builtin_amdgcn_mfma_f32_16x16x32_f16(a, b, c, 0, 0, 0);
}
static __device__ __forceinline__ float fsig(float x) {
  return 1.f / (1.f + __expf(-x));
}
static __device__ __forceinline__ float ftanh(float x) {
  return 1.f - 2.f / (1.f + __expf(2.f * x));  // overflow-safe
}

struct P {
  const u16 *w1h, *weff, *w1x, *w2, *w3, *wdec, *fr;
  const float *br, *ba, *b2s, *b3s, *dec_b;
  u16 *h0, *h1, *h2;
  float* out;
  u32* bar;
};

// B-frag (h as B-operand): lane(q,c) needs h[b=bt*16+c][k=kt*32+q*8+j].
// h layout [k>>2][b][4]: two h4 loads at (kt*8+2q)*256 + (bt*16+c)*4, +256.
template<int NKT>
static __device__ __forceinline__ void gemm_wreg(f4& acc, const u16* __restrict__ h,
                                                 const h8* wr, int kh, int bt,
                                                 int q, int c) {
#pragma unroll
  for (int jj = 0; jj < NKT; ++jj) {
    int kt = kh * 16 + jj;
    const u16* hp = h + (size_t)(kt * 8 + 2 * q) * 256 + (bt * 16 + c) * 4;
    h8 b;
    *(h4*)&b = *(const h4*)hp;
    *((h4*)&b + 1) = *(const h4*)(hp + 256);
    acc = mfma16(wr[jj], b, acc);
  }
}

// A (weights) from LDS frag store [kt][lane][8].
static __device__ __forceinline__ void gemm_wlds(f4& acc, const u16* __restrict__ h,
                                                 const u16* lw, int ktbase, int kh,
                                                 int bt, int q, int c, int lane) {
#pragma unroll
  for (int jj = 0; jj < 16; ++jj) {
    int kt = kh * 16 + jj;
    h8 a = *(const h8*)(lw + (size_t)((ktbase + kt) * 64 + lane) * 8);
    const u16* hp = h + (size_t)(kt * 8 + 2 * q) * 256 + (bt * 16 + c) * 4;
    h8 b;
    *(h4*)&b = *(const h4*)hp;
    *((h4*)&b + 1) = *(const h4*)(hp + 256);
    acc = mfma16(a, b, acc);
  }
}

// Frame [64][192] row-major, K=192 (6 kt), kh==0 only.
static __device__ __forceinline__ void gemm_fr(f4& acc, const u16* __restrict__ frt,
                                               const u16* lwx, int bt, int q, int c,
                                               int lane) {
#pragma unroll
  for (int kt = 0; kt < 6; ++kt) {
    h8 a = *(const h8*)(lwx + (size_t)(kt * 64 + lane) * 8);
    h8 b = *(const h8*)(frt + (size_t)(bt * 16 + c) * 192 + kt * 32 + q * 8);
    acc = mfma16(a, b, acc);
  }
}

__launch_bounds__(512, 2)
__global__ void lstm_main(P p) {
  const int ng = blockIdx.x;        // owns hidden units [4ng, 4ng+4)
  const int tid = threadIdx.x;
  const int lane = tid & 63;
  const int w = tid >> 6;           // 8 waves
  const int kh = w & 1;             // K-half (512)
  const int bt = w >> 1;            // batch tile [16bt, 16bt+16)
  const int c = lane & 15;
  const int q = lane >> 4;          // = unit_local for D

  __shared__ u16 lds_w2[64 * 512];        // 64 KB  A-frags [kt][lane][8]
  __shared__ u16 lds_w3[64 * 512];        // 64 KB
  __shared__ u16 lds_w1x[6 * 512];        // 6 KB
  __shared__ f4 part[2][4][64];           // 8 KB   kh0 partials [parity][bt]
  __shared__ u32 flags[2][4];
  __shared__ u32 arrv;
  __shared__ float decp[8][64];           // 2 KB

  // ---- one-time staging ----
  {
    const uint4* s2 = (const uint4*)(p.w2 + (size_t)ng * 64 * 512);
    const uint4* s3 = (const uint4*)(p.w3 + (size_t)ng * 64 * 512);
    const uint4* sx = (const uint4*)(p.w1x + (size_t)ng * 6 * 512);
    uint4* d2 = (uint4*)lds_w2;
    uint4* d3 = (uint4*)lds_w3;
    uint4* dx = (uint4*)lds_w1x;
    for (int i = tid; i < 4096; i += 512) { d2[i] = s2[i]; d3[i] = s3[i]; }
    if (tid < 384) dx[tid] = sx[tid];
    if (tid == 0) { arrv = 0; flags[0][0] = flags[0][1] = flags[0][2] = flags[0][3] = 0;
                    flags[1][0] = flags[1][1] = flags[1][2] = flags[1][3] = 0; }
  }
  // w1h/weff A-frags in regs: 16 kt each (this wave's K-half) = 128 VGPR
  h8 r_w1h[16], r_weff[16];
#pragma unroll
  for (int jj = 0; jj < 16; ++jj) {
    r_w1h[jj] = *(const h8*)(p.w1h + (size_t)((ng * 32 + kh * 16 + jj) * 64 + lane) * 8);
    r_weff[jj] = *(const h8*)(p.weff + (size_t)((ng * 32 + kh * 16 + jj) * 64 + lane) * 8);
  }
  // per-lane biases: gate r of unit ng*4+q
  float rb_r[4], rb_a[4], rb2[4], rb3[4];
#pragma unroll
  for (int r = 0; r < 4; ++r) {
    int idx = r * 1024 + ng * 4 + q;
    rb_r[r] = p.br[idx]; rb_a[r] = p.ba[idx];
    rb2[r] = p.b2s[idx]; rb3[r] = p.b3s[idx];
  }
  const float dec_bng = (ng < 171) ? p.dec_b[ng] : 0.f;
  __syncthreads();

  float cr0 = 0.f, cr1 = 0.f, cr2 = 0.f;  // c-state: (unit q, batch bt*16+c)
  u32 pub = 0;

  auto waitall = [&]() {  // wave 0 polls 256 slots for >= pub; others park
    if (w == 0) {
      for (;;) {
        u32 v0 = __hip_atomic_load(p.bar + lane, __ATOMIC_RELAXED, __HIP_MEMORY_SCOPE_AGENT);
        u32 v1 = __hip_atomic_load(p.bar + 64 + lane, __ATOMIC_RELAXED, __HIP_MEMORY_SCOPE_AGENT);
        u32 v2 = __hip_atomic_load(p.bar + 128 + lane, __ATOMIC_RELAXED, __HIP_MEMORY_SCOPE_AGENT);
        u32 v3 = __hip_atomic_load(p.bar + 192 + lane, __ATOMIC_RELAXED, __HIP_MEMORY_SCOPE_AGENT);
        u32 m01 = v0 < v1 ? v0 : v1;
        u32 m23 = v2 < v3 ? v2 : v3;
        u32 mn = m01 < m23 ? m01 : m23;
        if (__all((int)(mn >= pub))) break;
      }
    }
    __syncthreads();
  };

  // kh0: hand partial to pair via LDS flag.  kh1: reduce, nonlin, c-state,
  // shfl-pack, 128B store, drain, arrive (last of 4 publishes slot = pub).
  auto finish = [&](f4 acc, float& cst, const float* rb, u16* hw) {
    int par = pub & 1;
    if (kh == 0) {
      part[par][bt][lane] = acc;
      __builtin_amdgcn_s_waitcnt(0xC07F);  // lgkmcnt(0): data before flag
      if (lane == 0) *(volatile u32*)&flags[par][bt] = pub;
    } else {
      volatile u32* fp = &flags[par][bt];
      while (*fp != pub) {}
      f4 pt = part[par][bt][lane];
      float s0 = acc[0] + pt[0] + rb[0];
      float s1 = acc[1] + pt[1] + rb[1];
      float s2 = acc[2] + pt[2] + rb[2];
      float s3 = acc[3] + pt[3] + rb[3];
      float iv = fsig(s0), fv = fsig(s1), gv = ftanh(s2), ov = fsig(s3);
      float cn = fv * cst + iv * gv;
      cst = cn;
      f16 hh = (f16)(ov * ftanh(cn));
      u32 bits = (u32)*(const u16*)&hh;
      int srcA = ((lane & 1) * 2) * 16 + (lane >> 1);  // (b=lane>>1, q=2(lane&1))
      u32 v0 = __shfl(bits, srcA, 64);
      u32 v1 = __shfl(bits, srcA + 16, 64);
      if (lane < 32) {
        u32 pk = v0 | (v1 << 16);
        u32* dst = (u32*)hw + (size_t)ng * 128 + bt * 32 + lane;
        __hip_atomic_store(dst, pk, __ATOMIC_RELAXED, __HIP_MEMORY_SCOPE_AGENT);
      }
      __builtin_amdgcn_s_waitcnt(0x0F70);  // vmcnt(0): h at coherence point
      if (lane == 0) {
        u32 prev = atomicAdd(&arrv, 1u);
        if (prev == pub * 4u - 1u)
          __hip_atomic_store(p.bar + ng, pub, __ATOMIC_RELAXED, __HIP_MEMORY_SCOPE_AGENT);
      }
    }
  };

  auto dec_partial = [&](const u16* __restrict__ h2b) {
    if (ng < 171) {
      float s = 0.f;
      const u16* hp = h2b + (size_t)w * 32 * 256 + lane * 4;
      const u16* wp = p.wdec + (size_t)ng * 1024 + w * 128;
#pragma unroll 8
      for (int i = 0; i < 32; ++i) {
        h4 hv = *(const h4*)(hp + (size_t)i * 256);
        h4 wv = *(const h4*)(wp + i * 4);
#pragma unroll
        for (int jj = 0; jj < 4; ++jj) s += (float)hv[jj] * (float)wv[jj];
      }
      decp[w][lane] = s;
    }
  };

  for (int t = 0; t < 100; ++t) {
    const bool cond = (t % 10) < 5;
    const u16* h0r = p.h0 + (size_t)t * HSZ;
    const u16* h1r = p.h1 + (size_t)t * HSZ;
    const u16* h2r = p.h2 + (size_t)t * HSZ;
    u16* h0w = p.h0 + (size_t)(t + 1) * HSZ;
    u16* h1w = p.h1 + (size_t)(t + 1) * HSZ;
    u16* h2w = p.h2 + (size_t)(t + 1) * HSZ;

    // ---- window A: layer 1 ----
    {
      f4 acc = {0, 0, 0, 0};
      gemm_wreg<16>(acc, h0r, r_w1h, kh, bt, q, c);        // stale (B(t-1)-certified)
      if (cond) {
        if (kh == 0) gemm_fr(acc, p.fr + (size_t)t * 64 * 192, lds_w1x, bt, q, c, lane);
        // no grid wait: no fresh operand this window
      } else {
        waitall();                                          // h2(t-1) publishes
        gemm_wreg<16>(acc, h2r, r_weff, kh, bt, q, c);      // folded feedback
      }
      ++pub;
      finish(acc, cr0, cond ? rb_r : rb_a, h0w);
    }
    // ---- window B: layer 2 ----
    {
      f4 acc = {0, 0, 0, 0};
      if (cond) {
        waitall();  // certifies h1r (pub covers A(t) > C(t-1)) AND h0w
        gemm_wlds(acc, h1r, lds_w2, 32, kh, bt, q, c, lane);
      } else {
        gemm_wlds(acc, h1r, lds_w2, 32, kh, bt, q, c, lane);  // stale (A-certified)
        waitall();                                            // h0(t) publishes
      }
      gemm_wlds(acc, h0w, lds_w2, 0, kh, bt, q, c, lane);     // fresh
      ++pub;
      finish(acc, cr1, rb2, h1w);
    }
    // ---- window C: layer 3 (+ decoder t-1 on stale h2) ----
    {
      f4 acc = {0, 0, 0, 0};
      gemm_wlds(acc, h2r, lds_w3, 32, kh, bt, q, c, lane);   // stale (B-certified)
      if (t > 0) dec_partial(h2r);
      waitall();                                             // h1(t) publishes
      gemm_wlds(acc, h1w, lds_w3, 0, kh, bt, q, c, lane);    // fresh
      if (w == 2 && t > 0 && ng < 171) {                     // decp visible post-sync
        float o = dec_bng;
#pragma unroll
        for (int i = 0; i < 8; ++i) o += decp[i][lane];
        p.out[(size_t)lane * 17100 + (size_t)(t - 1) * 171 + ng] = o;
      }
      ++pub;
      finish(acc, cr2, rb3, h2w);
    }
  }
  // final decoder: out(99) from h2 slot 100
  waitall();
  dec_partial(p.h2 + (size_t)100 * HSZ);
  __syncthreads();
  if (w == 0 && ng < 171) {
    float o = dec_bng;
#pragma unroll
    for (int i = 0; i < 8; ++i) o += decp[i][lane];
    p.out[(size_t)lane * 17100 + (size_t)99 * 171 + ng] = o;
  }
}

// ------------------------- prep kernels -------------------------

// Pack [4096 x (KA+KB)] fp32 weights into MFMA-A fragments, [unit][gate] rows:
// tile row m=c -> torch row (c&3)*1024 + ng*4 + (c>>2).
// dst[((ng*nkt + kt)*64 + lane)*8 + j] = W[row][kt*32 + (lane>>4)*8 + j]
__global__ void pack_w_kernel(const float* __restrict__ srcA, int KA,
                              const float* __restrict__ srcB, int KB,
                              u16* __restrict__ dst, int nkt) {
  int blk = blockIdx.x;
  int ng = blk / nkt, kt = blk % nkt;
  int lane = threadIdx.x;
  int c = lane & 15, qq = lane >> 4;
  int row = (c & 3) * 1024 + ng * 4 + (c >> 2);
  int k0 = kt * 32 + qq * 8;
  alignas(16) u16 outv[8];
  if (k0 + 8 <= KA) {
    const float4* s = (const float4*)(srcA + (size_t)row * KA + k0);
    float4 a = s[0], b = s[1];
    float vv[8] = {a.x, a.y, a.z, a.w, b.x, b.y, b.z, b.w};
    for (int j = 0; j < 8; ++j) { f16 hv = (f16)vv[j]; outv[j] = *(u16*)&hv; }
  } else if (k0 >= KA && k0 + 8 <= KA + KB) {
    const float4* s = (const float4*)(srcB + (size_t)row * KB + (k0 - KA));
    float4 a = s[0], b = s[1];
    float vv[8] = {a.x, a.y, a.z, a.w, b.x, b.y, b.z, b.w};
    for (int j = 0; j < 8; ++j) { f16 hv = (f16)vv[j]; outv[j] = *(u16*)&hv; }
  } else {
    for (int j = 0; j < 8; ++j) {
      int k = k0 + j;
      float v = 0.f;
      if (k < KA) v = srcA[(size_t)row * KA + k];
      else if (k - KA < KB) v = srcB[(size_t)row * KB + (k - KA)];
      f16 hv = (f16)v;
      outv[j] = *(u16*)&hv;
    }
  }
  *(uint4*)(dst + ((size_t)blk * 64 + lane) * 8) = *(const uint4*)outv;
}

// W_eff[n][k] = sum_{r<171} w_ih1[n][r] * dec_w[r][k], MFMA-A packed fp16.
__global__ void pack_weff_kernel(const float* __restrict__ w_ih1,
                                 const float* __restrict__ dec_w, u16* __restrict__ dst) {
  int blk = blockIdx.x;  // ng*32 + kt
  int ng = blk >> 5, kt = blk & 31;
  int lane = threadIdx.x;
  int c = lane & 15, qq = lane >> 4;
  int row = (c & 3) * 1024 + ng * 4 + (c >> 2);
  int k0 = kt * 32 + qq * 8;
  float acc[8] = {0.f, 0.f, 0.f, 0.f, 0.f, 0.f, 0.f, 0.f};
  for (int r = 0; r < 171; ++r) {
    float wi = w_ih1[(size_t)row * 171 + r];
    const float* dw = dec_w + (size_t)r * 1024 + k0;
#pragma unroll
    for (int j = 0; j < 8; ++j) acc[j] += wi * dw[j];
  }
  alignas(16) u16 outv[8];
  for (int j = 0; j < 8; ++j) { f16 hv = (f16)acc[j]; outv[j] = *(u16*)&hv; }
  *(uint4*)(dst + ((size_t)blk * 64 + lane) * 8) = *(const uint4*)outv;
}

__global__ void prep_bias_kernel(const float* b_ih1, const float* b_hh1,
                                 const float* w_ih1, const float* dec_b,
                                 const float* b_ih2, const float* b_hh2,
                                 const float* b_ih3, const float* b_hh3,
                                 float* br, float* ba, float* b2, float* b3) {
  int n = blockIdx.x * 256 + threadIdx.x;  // 0..4095
  float s = b_ih1[n] + b_hh1[n];
  br[n] = s;
  float a = 0.f;
  for (int r = 0; r < 171; ++r) a += w_ih1[(size_t)n * 171 + r] * dec_b[r];
  ba[n] = s + a;  // autoregressive path: + W_ih1 @ dec_b
  b2[n] = b_ih2[n] + b_hh2[n];
  b3[n] = b_ih3[n] + b_hh3[n];
}

// real_seq [64][100][171] fp32 -> fr16 [100][64][192] fp16 (zero-padded K)
__global__ void pack_frames_kernel(const float* __restrict__ rs, u16* __restrict__ fr) {
  int i = blockIdx.x * 256 + threadIdx.x;
  int j = i % 192;
  int tb = i / 192;
  int b = tb % 64, t = tb / 64;
  float v = (j < 171) ? rs[((size_t)b * 100 + t) * 171 + j] : 0.f;
  f16 hv = (f16)v;
  fr[i] = *(u16*)&hv;
}

__global__ void pack_wdec_kernel(const float* __restrict__ dw, u16* __restrict__ dst) {
  int i = blockIdx.x * 256 + threadIdx.x;
  if (i < 171 * 1024) { f16 hv = (f16)dw[i]; dst[i] = *(u16*)&hv; }
}

// zero h slot 0 of each buffer (initial state) and the slot page
__global__ void zero_kernel(u32* h0, u32* h1, u32* h2, u32* bar) {
  int i = blockIdx.x * 256 + threadIdx.x;  // 0..32767
  h0[i] = 0; h1[i] = 0; h2[i] = 0;
  if (blockIdx.x < 8) bar[i] = 0;
}

extern "C" void kernel_launch(void* const* d_in, const int* in_sizes, int n_in,
                              void* d_out, int out_size, void* d_ws, size_t ws_size,
                              hipStream_t stream) {
  const float* real_seq = (const float*)d_in[0];
  const float* w_ih1 = (const float*)d_in[1];
  const float* w_hh1 = (const float*)d_in[2];
  const float* b_ih1 = (const float*)d_in[3];
  const float* b_hh1 = (const float*)d_in[4];
  const float* w_ih2 = (const float*)d_in[5];
  const float* w_hh2 = (const float*)d_in[6];
  const float* b_ih2 = (const float*)d_in[7];
  const float* b_hh2 = (const float*)d_in[8];
  const float* w_ih3 = (const float*)d_in[9];
  const float* w_hh3 = (const float*)d_in[10];
  const float* b_ih3 = (const float*)d_in[11];
  const float* b_hh3 = (const float*)d_in[12];
  const float* dec_w = (const float*)d_in[13];
  const float* dec_b = (const float*)d_in[14];

  char* ws = (char*)d_ws;
  size_t off = 0;
  auto alloc = [&](size_t bytes) {
    char* pp = ws + off;
    off += (bytes + 255) & ~(size_t)255;
    return pp;
  };
  u16* w1h  = (u16*)alloc(256ULL * 32 * 512 * 2);   // w_hh1 packed (A-frags)
  u16* weff = (u16*)alloc(256ULL * 32 * 512 * 2);   // W_ih1 @ dec_w packed
  u16* w1x  = (u16*)alloc(256ULL * 6 * 512 * 2);    // w_ih1 packed (K pad 192)
  u16* w2   = (u16*)alloc(256ULL * 64 * 512 * 2);   // [w_ih2 | w_hh2] packed
  u16* w3   = (u16*)alloc(256ULL * 64 * 512 * 2);   // [w_ih3 | w_hh3] packed
  u16* wdec = (u16*)alloc(171ULL * 1024 * 2);       // dec_w fp16 row-major
  u16* fr   = (u16*)alloc(100ULL * 64 * 192 * 2);   // frames fp16 padded
  u16* h0   = (u16*)alloc(101ULL * HSZ * 2);        // rotating h, [k/4][b][4]
  u16* h1   = (u16*)alloc(101ULL * HSZ * 2);
  u16* h2   = (u16*)alloc(101ULL * HSZ * 2);
  float* br  = (float*)alloc(4096 * 4);
  float* ba  = (float*)alloc(4096 * 4);
  float* b2s = (float*)alloc(4096 * 4);
  float* b3s = (float*)alloc(4096 * 4);
  u32* bar   = (u32*)alloc(8192);
  (void)ws_size; (void)in_sizes; (void)n_in; (void)out_size;  // needs ~91 MiB ws

  pack_w_kernel<<<256 * 32, 64, 0, stream>>>(w_hh1, 1024, nullptr, 0, w1h, 32);
  pack_w_kernel<<<256 * 6, 64, 0, stream>>>(w_ih1, 171, nullptr, 0, w1x, 6);
  pack_w_kernel<<<256 * 64, 64, 0, stream>>>(w_ih2, 1024, w_hh2, 1024, w2, 64);
  pack_w_kernel<<<256 * 64, 64, 0, stream>>>(w_ih3, 1024, w_hh3, 1024, w3, 64);
  pack_weff_kernel<<<256 * 32, 64, 0, stream>>>(w_ih1, dec_w, weff);
  pack_wdec_kernel<<<(171 * 1024 + 255) / 256, 256, 0, stream>>>(dec_w, wdec);
  pack_frames_kernel<<<100 * 64 * 192 / 256, 256, 0, stream>>>(real_seq, fr);
  prep_bias_kernel<<<16, 256, 0, stream>>>(b_ih1, b_hh1, w_ih1, dec_b,
                                           b_ih2, b_hh2, b_ih3, b_hh3, br, ba, b2s, b3s);
  zero_kernel<<<128, 256, 0, stream>>>((u32*)h0, (u32*)h1, (u32*)h2, bar);

  P p{w1h, weff, w1x, w2, w3, wdec, fr, br, ba, b2s, b3s, dec_b,
      h0, h1, h2, (float*)d_out, bar};
  lstm_main<<<256, 512, 0, stream>>>(p);
}